// Round 8
// baseline (174.540 us; speedup 1.0000x reference)
//
#include <hip/hip_runtime.h>
#include <stdint.h>

// ---------------------------------------------------------------------------
// LinearBlock: out[b, p*8+o] = clip((sum_{q,i} Wq[p,q,o,i]*xq[b,q*8+i])^2, 0, 6)
// Exact int8 path (unchanged, 7x verified):
//   xq = xu/255, wq = wi*2/127, dot=(sum xu*wi)*2/(255*127); zero-point via
//   xs=xu-128 and +128*rowsum[n].
//
// Round 8: per-wave FRAGMENT PIPELINING. Double-banked frags (afA/afB,
// bf0/bf1); phase k issues phase k+1's ds_reads and waits lgkmcnt(N_new) so
// MFMA(k) depends only on reads issued during MFMA(k-1) -> LDS pipe busy
// during matrix bursts. Quad order (0,0)(0,1)(1,0)(1,1) = WAR-free rotation.
// vmcnt ledger: WVM(2) at P0/P1/P3 (waited DMAs >=3 phases old), never 0.
// Plus probe_mfma (MFMA-only, same phase skeleton) to measure the i8 pipe
// at 2 waves/SIMD; writes to d_out, fully overwritten by the real GEMM.
// ---------------------------------------------------------------------------

typedef int i32x4 __attribute__((ext_vector_type(4)));

#define B_DIM   16384
#define IN_DIM  2048
#define OUT_DIM 2048

#define BM 256
#define BN 256
#define BK 128
#define KTILES (IN_DIM / BK)   // 16
#define HALF   16384           // bytes per half-tile (128 rows x 128 B)
#define BUFB   (4 * HALF)      // 64 KB: [Aa][Ab][Ba][Bb]

__device__ __forceinline__ void async16(const void* g, void* l) {
    __builtin_amdgcn_global_load_lds(
        (const __attribute__((address_space(1))) void*)g,
        (__attribute__((address_space(3))) void*)l, 16, 0, 0);
}

// --- quantize x: float [B,IN] -> int8 (value-128) [B,IN], 16 elems/thread ---
__global__ __launch_bounds__(256) void quant_x_kernel(const float* __restrict__ x,
                                                      int8_t* __restrict__ xq) {
    int i = blockIdx.x * 256 + threadIdx.x;
    const float4* xv = (const float4*)x + (size_t)i * 4;
    union { int8_t c[16]; i32x4 v; } u;
#pragma unroll
    for (int j = 0; j < 4; ++j) {
        float4 v = xv[j];
        float f[4] = {v.x, v.y, v.z, v.w};
#pragma unroll
        for (int e = 0; e < 4; ++e) {
            float c = fminf(fmaxf(f[e], 0.0f), 1.0f);
            int q = (int)rintf(c * 255.0f) - 128;
            u.c[j * 4 + e] = (int8_t)q;
        }
    }
    *((i32x4*)xq + i) = u.v;
}

// --- quantize + relayout weight: [P=256,Q=256,8,8] f32 -> [2048][2048] int8
__global__ __launch_bounds__(256) void quant_w_kernel(const float* __restrict__ w,
                                                      int8_t* __restrict__ wq,
                                                      int* __restrict__ rowsum) {
    int p = blockIdx.x;
    int t = threadIdx.x;
    const float* wp = w + (size_t)p * 16384;
    int n = p * 8 + (t & 7);
    int lsum = 0;
#pragma unroll
    for (int s = 0; s < 8; ++s) {
        int g = t + s * 256;
        float4 v0 = *(const float4*)(wp + g * 8);
        float4 v1 = *(const float4*)(wp + g * 8 + 4);
        float f[8] = {v0.x, v0.y, v0.z, v0.w, v1.x, v1.y, v1.z, v1.w};
        union { int8_t c[8]; long long ll; } u;
#pragma unroll
        for (int e = 0; e < 8; ++e) {
            float c = fminf(fmaxf(f[e], -2.0f), 2.0f);
            int q = (int)rintf(c * 63.5f);
            u.c[e] = (int8_t)q;
            lsum += q;
        }
        int kg = g >> 3;
        *(long long*)(wq + (size_t)n * 2048 + kg * 8) = u.ll;
    }
    atomicAdd(&rowsum[n], lsum);
}

#define SB0 __builtin_amdgcn_sched_barrier(0)
#define BAR __builtin_amdgcn_s_barrier()
#define WLG(n) asm volatile("s_waitcnt lgkmcnt(" #n ")" ::: "memory")
#define WVM(n) asm volatile("s_waitcnt vmcnt(" #n ")" ::: "memory")
#define LD(p) (*(const i32x4*)(p))

// 16-MFMA quadrant: acc[MH][NH], mf(4) x nf(2) x kk(2)
#define CLPH(MH, NH, AF, BF)                                                  \
    _Pragma("unroll")                                                         \
    for (int mf = 0; mf < 4; ++mf)                                            \
        _Pragma("unroll")                                                     \
        for (int nf = 0; nf < 2; ++nf)                                        \
            _Pragma("unroll")                                                 \
            for (int kk = 0; kk < 2; ++kk)                                    \
                acc[MH][NH][mf][nf] = __builtin_amdgcn_mfma_i32_16x16x64_i8(  \
                    AF[2 * mf + kk], BF[2 * nf + kk], acc[MH][NH][mf][nf], 0, 0, 0);

#define RD_A8(DST, BP)                                                        \
    DST[0] = LD((BP) + aoff0);        DST[1] = LD((BP) + (aoff0 ^ 64));       \
    DST[2] = LD((BP) + aoff0 + 2048); DST[3] = LD((BP) + ((aoff0+2048) ^ 64));\
    DST[4] = LD((BP) + aoff0 + 4096); DST[5] = LD((BP) + ((aoff0+4096) ^ 64));\
    DST[6] = LD((BP) + aoff0 + 6144); DST[7] = LD((BP) + ((aoff0+6144) ^ 64));
#define RD_B4(DST, BP)                                                        \
    DST[0] = LD((BP) + boff0);        DST[1] = LD((BP) + (boff0 ^ 64));       \
    DST[2] = LD((BP) + boff0 + 2048); DST[3] = LD((BP) + ((boff0+2048) ^ 64));

// Steady-state K-tile on buffer BB; stages tile KT2 into BB^1; P3 pre-reads
// next tile's Aa/Ba fragments from BB^1.
#define DO_TILE(BB, KT2) do {                                                 \
    const int8_t* base  = lds + (BB) * BUFB;                                  \
    const int8_t* nbase = lds + ((BB) ^ 1) * BUFB;                            \
    int8_t* dst = lds + ((BB) ^ 1) * BUFB;                                    \
    const int kb = (KT2) * BK;                                                \
    /* P0: MFMA(0,0) afA,bf0 | stage Aa' | read bf1<-Bb */                    \
    WVM(2); BAR;                                                              \
    async16(gAa + kb, dst + t16); async16(gAa + 131072 + kb, dst + 8192 + t16);\
    RD_B4(bf1, base + 3 * HALF)                                               \
    WLG(4); SB0;                                                              \
    __builtin_amdgcn_s_setprio(1); CLPH(0, 0, afA, bf0)                       \
    __builtin_amdgcn_s_setprio(0); SB0;                                       \
    /* P1: MFMA(0,1) afA,bf1 | stage Ba' | read afB<-Ab */                    \
    WVM(2); BAR;                                                              \
    async16(gBa + kb, dst + 2 * HALF + t16);                                  \
    async16(gBa + 131072 + kb, dst + 2 * HALF + 8192 + t16);                  \
    RD_A8(afB, base + HALF)                                                   \
    WLG(8); SB0;                                                              \
    __builtin_amdgcn_s_setprio(1); CLPH(0, 1, afA, bf1)                       \
    __builtin_amdgcn_s_setprio(0); SB0;                                       \
    /* P2: MFMA(1,0) afB,bf0 | stage Bb' | no reads */                        \
    async16(gBb + kb, dst + 3 * HALF + t16);                                  \
    async16(gBb + 131072 + kb, dst + 3 * HALF + 8192 + t16);                  \
    WLG(0); SB0;                                                              \
    __builtin_amdgcn_s_setprio(1); CLPH(1, 0, afB, bf0)                       \
    __builtin_amdgcn_s_setprio(0); SB0;                                       \
    /* P3: MFMA(1,1) afB,bf1 | stage Ab' | read afA,bf0 <- next Aa,Ba */      \
    WVM(2); BAR;                                                              \
    async16(gAb + kb, dst + HALF + t16);                                      \
    async16(gAb + 131072 + kb, dst + HALF + 8192 + t16);                      \
    RD_A8(afA, nbase)                                                         \
    RD_B4(bf0, nbase + 2 * HALF)                                              \
    WLG(12); SB0;                                                             \
    __builtin_amdgcn_s_setprio(1); CLPH(1, 1, afB, bf1)                       \
    __builtin_amdgcn_s_setprio(0); SB0;                                       \
} while (0)

// Last K-tile (buffer 1): no staging, no pre-reads.
#define DO_TAIL() do {                                                        \
    const int8_t* base = lds + BUFB;                                          \
    WVM(2); BAR;                                                              \
    RD_B4(bf1, base + 3 * HALF)                                               \
    WLG(4); SB0;                                                              \
    __builtin_amdgcn_s_setprio(1); CLPH(0, 0, afA, bf0)                       \
    __builtin_amdgcn_s_setprio(0); SB0;                                       \
    WVM(0); BAR;                                                              \
    RD_A8(afB, base + HALF)                                                   \
    WLG(8); SB0;                                                              \
    __builtin_amdgcn_s_setprio(1); CLPH(0, 1, afA, bf1)                       \
    __builtin_amdgcn_s_setprio(0); SB0;                                       \
    WLG(0); SB0;                                                              \
    __builtin_amdgcn_s_setprio(1); CLPH(1, 0, afB, bf0)                       \
    __builtin_amdgcn_s_setprio(0); SB0;                                       \
    __builtin_amdgcn_s_setprio(1); CLPH(1, 1, afB, bf1)                       \
    __builtin_amdgcn_s_setprio(0); SB0;                                       \
} while (0)

// --- int8 GEMM: 256x256, BK=128, 8 waves, dbuf, fragment-pipelined ---
__global__ __launch_bounds__(512, 2) void gemm_i8_kernel(const int8_t* __restrict__ A,
                                                         const int8_t* __restrict__ W,
                                                         const int* __restrict__ rowsum,
                                                         float* __restrict__ out) {
    extern __shared__ int8_t lds[];   // 2 * 64 KB

    int bid = blockIdx.x;
    int wg = (bid & 7) * 64 + (bid >> 3);
    int tm = wg >> 3;
    int tn = wg & 7;
    int brow = tm * BM;
    int bcol = tn * BN;

    int tid  = threadIdx.x;
    int lane = tid & 63;
    int wv   = tid >> 6;
    int wr = wv >> 2, wc = wv & 3;
    int l15 = lane & 15;
    int kg  = lane >> 4;

    int csw = (tid & 7) ^ ((tid >> 4) & 7);
    const int8_t* gAa = A + (size_t)(brow + (tid >> 3)) * IN_DIM + csw * 16;
    const int8_t* gAb = gAa + 128 * IN_DIM;
    const int8_t* gBa = W + (size_t)(bcol + (tid >> 3)) * IN_DIM + csw * 16;
    const int8_t* gBb = gBa + 128 * IN_DIM;
    const int t16 = tid * 16;

    const int xsw   = (l15 >> 1) & 7;
    const int koff0 = ((kg ^ xsw) << 4);
    const int aoff0 = (wr * 64 + l15) * BK + koff0;   // + mf*2048, ^64 for kk=1
    const int boff0 = (wc * 32 + l15) * BK + koff0;   // + nf*2048

    i32x4 acc[2][2][4][2];
#pragma unroll
    for (int mh = 0; mh < 2; ++mh)
#pragma unroll
        for (int nh = 0; nh < 2; ++nh)
#pragma unroll
            for (int mf = 0; mf < 4; ++mf)
#pragma unroll
                for (int nf = 0; nf < 2; ++nf)
                    acc[mh][nh][mf][nf] = (i32x4){0, 0, 0, 0};
    i32x4 afA[8], afB[8], bf0[4], bf1[4];

    // ---- prologue: stage tile0 (order Aa,Ba,Bb,Ab); pre-read Aa,Ba frags ----
    async16(gAa, lds + t16);
    async16(gAa + 131072, lds + 8192 + t16);
    async16(gBa, lds + 2 * HALF + t16);
    async16(gBa + 131072, lds + 2 * HALF + 8192 + t16);
    async16(gBb, lds + 3 * HALF + t16);
    async16(gBb + 131072, lds + 3 * HALF + 8192 + t16);
    async16(gAb, lds + HALF + t16);
    async16(gAb + 131072, lds + HALF + 8192 + t16);
    WVM(4); BAR;                     // Aa0, Ba0 landed
    RD_A8(afA, lds)
    RD_B4(bf0, lds + 2 * HALF)

    // ---- main loop: tiles 0..14 stage 1..15; tile 15 is the tail ----
#pragma unroll 1
    for (int i = 0; i < 7; ++i) {
        DO_TILE(0, 2 * i + 1);
        DO_TILE(1, 2 * i + 2);
    }
    DO_TILE(0, 15);
    DO_TAIL();

    // ---- epilogue: zero-point, scale, photodetect square, ReLUN(6) ----
    const float scale = (float)(2.0 / 32385.0);
#pragma unroll
    for (int nh = 0; nh < 2; ++nh)
#pragma unroll
        for (int nf = 0; nf < 2; ++nf) {
            int col = bcol + nh * 128 + wc * 32 + nf * 16 + l15;
            int rs128 = rowsum[col] << 7;
#pragma unroll
            for (int mh = 0; mh < 2; ++mh)
#pragma unroll
                for (int mf = 0; mf < 4; ++mf) {
                    int row0 = brow + mh * 128 + wr * 64 + mf * 16 + kg * 4;
#pragma unroll
                    for (int r = 0; r < 4; ++r) {
                        float f = (float)(acc[mh][nh][mf][nf][r] + rs128) * scale;
                        f = f * f;
                        f = fminf(f, 6.0f);
                        out[(size_t)(row0 + r) * OUT_DIM + col] = f;
                    }
                }
        }
}

// --- probe: MFMA-only with the same phase/barrier skeleton; measures the ---
// --- i8 matrix-pipe rate at 2 waves/SIMD. Writes d_out, later overwritten. --
__global__ __launch_bounds__(512, 2) void probe_mfma(const float* __restrict__ X,
                                                     float* __restrict__ out) {
    extern __shared__ int8_t plds[];
    int tid = threadIdx.x;
    // opaque operand init (from global memory; values irrelevant)
    i32x4 af[8], bf0[4], bf1[4];
    const i32x4* src = (const i32x4*)X + (tid & 63);
#pragma unroll
    for (int i = 0; i < 8; ++i) af[i] = src[i];
#pragma unroll
    for (int i = 0; i < 4; ++i) { bf0[i] = src[8 + i]; bf1[i] = src[12 + i]; }
    plds[tid] = (int8_t)tid;          // keep LDS allocation live
    __syncthreads();

    i32x4 acc[2][2][4][2];
#pragma unroll
    for (int mh = 0; mh < 2; ++mh)
#pragma unroll
        for (int nh = 0; nh < 2; ++nh)
#pragma unroll
            for (int mf = 0; mf < 4; ++mf)
#pragma unroll
                for (int nf = 0; nf < 2; ++nf)
                    acc[mh][nh][mf][nf] = (i32x4){0, 0, 0, 0};

#pragma unroll 1
    for (int t = 0; t < KTILES; ++t) {
        BAR;
        __builtin_amdgcn_s_setprio(1); CLPH(0, 0, af, bf0)
        __builtin_amdgcn_s_setprio(0); SB0;
        BAR;
        __builtin_amdgcn_s_setprio(1); CLPH(0, 1, af, bf1)
        __builtin_amdgcn_s_setprio(0); SB0;
        BAR;
        __builtin_amdgcn_s_setprio(1); CLPH(1, 0, af, bf0)
        __builtin_amdgcn_s_setprio(0); SB0;
        BAR;
        __builtin_amdgcn_s_setprio(1); CLPH(1, 1, af, bf1)
        __builtin_amdgcn_s_setprio(0); SB0;
    }

    float s = 0.f;
#pragma unroll
    for (int mh = 0; mh < 2; ++mh)
#pragma unroll
        for (int nh = 0; nh < 2; ++nh)
#pragma unroll
            for (int mf = 0; mf < 4; ++mf)
#pragma unroll
                for (int nf = 0; nf < 2; ++nf)
#pragma unroll
                    for (int r = 0; r < 4; ++r)
                        s += (float)acc[mh][nh][mf][nf][r];
    out[(size_t)blockIdx.x * 512 + tid] = s;   // overwritten by gemm later
}

extern "C" void kernel_launch(void* const* d_in, const int* in_sizes, int n_in,
                              void* d_out, int out_size, void* d_ws, size_t ws_size,
                              hipStream_t stream) {
    const float* x  = (const float*)d_in[0];
    const float* wt = (const float*)d_in[1];
    float* out = (float*)d_out;

    char* ws = (char*)d_ws;
    int8_t* xq = (int8_t*)ws;                                   // 32 MB
    int8_t* wq = (int8_t*)(ws + (size_t)B_DIM * IN_DIM);        // 4 MB
    int*    rowsum = (int*)(ws + (size_t)B_DIM * IN_DIM
                               + (size_t)OUT_DIM * IN_DIM);     // 8 KB

    probe_mfma<<<256, 512, 2 * BUFB, stream>>>(x, out);
    hipMemsetAsync(rowsum, 0, OUT_DIM * sizeof(int), stream);
    quant_x_kernel<<<(B_DIM * IN_DIM / 16) / 256, 256, 0, stream>>>(x, xq);
    quant_w_kernel<<<256, 256, 0, stream>>>(wt, wq, rowsum);
    gemm_i8_kernel<<<(B_DIM / BM) * (OUT_DIM / BN), 512, 2 * BUFB, stream>>>(xq, wq, rowsum, out);
}

// Round 9
// 123.749 us; speedup vs baseline: 1.4104x; 1.4104x over previous
//
#include <hip/hip_runtime.h>
#include <stdint.h>

// ---------------------------------------------------------------------------
// LinearBlock: out[b, p*8+o] = clip((sum_{q,i} Wq[p,q,o,i]*xq[b,q*8+i])^2, 0, 6)
// Exact int8 path (8x verified):
//   xq = xu/255, wq = wi*2/127, dot=(sum xu*wi)*2/(255*127); zero-point via
//   xs=xu-128 and +128*rowsum[n].
//
// Round 9: mfma_i32_32x32x32_i8 + register-budgeted fragment pipelining.
// 256x256, BK=128, 8 waves (2Mx4N), wave tile 128x64 as 4x2 32x32 frags
// (acc 128 VGPR). Per tile: 4 k-phases x 8 MFMA; phase ks issues phase
// ks+1's 6 ds_reads BEFORE waiting lgkmcnt(6) on its own bank -> next
// phase's LDS service overlaps this phase's MFMA. ONE barrier per tile;
// WVM(0) waits DMAs issued a full tile (~2600 cyc) earlier. Double-banked
// frags = 48 VGPR (fits; round-8's 96-VGPR version spilled).
// ---------------------------------------------------------------------------

typedef int i32x4  __attribute__((ext_vector_type(4)));
typedef int i32x16 __attribute__((ext_vector_type(16)));

#define B_DIM   16384
#define IN_DIM  2048
#define OUT_DIM 2048

#define BM 256
#define BN 256
#define BK 128
#define KTILES (IN_DIM / BK)   // 16
#define ATILE  (BM * BK)       // 32768 bytes
#define BUFB   (2 * ATILE)     // 65536 bytes (A half + B half)

__device__ __forceinline__ void async16(const void* g, void* l) {
    __builtin_amdgcn_global_load_lds(
        (const __attribute__((address_space(1))) void*)g,
        (__attribute__((address_space(3))) void*)l, 16, 0, 0);
}

// --- quantize x: float [B,IN] -> int8 (value-128) [B,IN], 16 elems/thread ---
__global__ __launch_bounds__(256) void quant_x_kernel(const float* __restrict__ x,
                                                      int8_t* __restrict__ xq) {
    int i = blockIdx.x * 256 + threadIdx.x;
    const float4* xv = (const float4*)x + (size_t)i * 4;
    union { int8_t c[16]; i32x4 v; } u;
#pragma unroll
    for (int j = 0; j < 4; ++j) {
        float4 v = xv[j];
        float f[4] = {v.x, v.y, v.z, v.w};
#pragma unroll
        for (int e = 0; e < 4; ++e) {
            float c = fminf(fmaxf(f[e], 0.0f), 1.0f);
            int q = (int)rintf(c * 255.0f) - 128;
            u.c[j * 4 + e] = (int8_t)q;
        }
    }
    *((i32x4*)xq + i) = u.v;
}

// --- quantize + relayout weight: [P=256,Q=256,8,8] f32 -> [2048][2048] int8
__global__ __launch_bounds__(256) void quant_w_kernel(const float* __restrict__ w,
                                                      int8_t* __restrict__ wq,
                                                      int* __restrict__ rowsum) {
    int p = blockIdx.x;
    int t = threadIdx.x;
    const float* wp = w + (size_t)p * 16384;
    int n = p * 8 + (t & 7);
    int lsum = 0;
#pragma unroll
    for (int s = 0; s < 8; ++s) {
        int g = t + s * 256;
        float4 v0 = *(const float4*)(wp + g * 8);
        float4 v1 = *(const float4*)(wp + g * 8 + 4);
        float f[8] = {v0.x, v0.y, v0.z, v0.w, v1.x, v1.y, v1.z, v1.w};
        union { int8_t c[8]; long long ll; } u;
#pragma unroll
        for (int e = 0; e < 8; ++e) {
            float c = fminf(fmaxf(f[e], -2.0f), 2.0f);
            int q = (int)rintf(c * 63.5f);
            u.c[e] = (int8_t)q;
            lsum += q;
        }
        int kg = g >> 3;
        *(long long*)(wq + (size_t)n * 2048 + kg * 8) = u.ll;
    }
    atomicAdd(&rowsum[n], lsum);
}

#define SB0 __builtin_amdgcn_sched_barrier(0)
#define SP1 __builtin_amdgcn_s_setprio(1)
#define SP0 __builtin_amdgcn_s_setprio(0)
#define WLG(n) asm volatile("s_waitcnt lgkmcnt(" #n ")" ::: "memory")
#define WVM0   asm volatile("s_waitcnt vmcnt(0)" ::: "memory")
#define LD(p) (*(const i32x4*)(p))
#define MFMA32(a, b, c) __builtin_amdgcn_mfma_i32_32x32x32_i8(a, b, c, 0, 0, 0)

// read one k-phase's fragments into a bank: A m0..3 (4), B n0..1 (2)
#define RD6(AV, BV, KOFF)                                                     \
    AV[0] = LD(la + arowO + (KOFF));                                          \
    AV[1] = LD(la + arowO + 4096 + (KOFF));                                   \
    AV[2] = LD(la + arowO + 8192 + (KOFF));                                   \
    AV[3] = LD(la + arowO + 12288 + (KOFF));                                  \
    BV[0] = LD(lb + browO + (KOFF));                                          \
    BV[1] = LD(lb + browO + 4096 + (KOFF));

#define MM8(AV, BV)                                                           \
    _Pragma("unroll")                                                         \
    for (int m = 0; m < 4; ++m)                                               \
        _Pragma("unroll")                                                     \
        for (int n = 0; n < 2; ++n)                                           \
            acc[m][n] = MFMA32(AV[m], BV[n], acc[m][n]);

// One K-tile on buffer BB; when STG, stages tile KT2 into BB^1.
#define DO_TILE(BB, KT2, STG) do {                                            \
    const int8_t* la = lds + (BB) * BUFB;                                     \
    const int8_t* lb = la + ATILE;                                            \
    int8_t* dst = lds + ((BB) ^ 1) * BUFB;                                    \
    WVM0;                                                                     \
    __builtin_amdgcn_s_barrier();                                             \
    if (STG) {                                                                \
        const int kb = (KT2) * BK;                                            \
        async16(gA + kb, dst + t16);                                          \
        async16(gA + 131072 + kb, dst + 8192 + t16);                          \
        async16(gA + 262144 + kb, dst + 16384 + t16);                         \
        async16(gA + 393216 + kb, dst + 24576 + t16);                         \
        async16(gB + kb, dst + ATILE + t16);                                  \
        async16(gB + 131072 + kb, dst + ATILE + 8192 + t16);                  \
        async16(gB + 262144 + kb, dst + ATILE + 16384 + t16);                 \
        async16(gB + 393216 + kb, dst + ATILE + 24576 + t16);                 \
    }                                                                         \
    RD6(aX, bX, k0)                                                           \
    RD6(aY, bY, k1)                                                           \
    WLG(6); SB0;                                                              \
    SP1; MM8(aX, bX) SP0;                                                     \
    RD6(aX, bX, k2)                                                           \
    WLG(6); SB0;                                                              \
    SP1; MM8(aY, bY) SP0;                                                     \
    RD6(aY, bY, k3)                                                           \
    WLG(6); SB0;                                                              \
    SP1; MM8(aX, bX) SP0;                                                     \
    WLG(0); SB0;                                                              \
    SP1; MM8(aY, bY) SP0;                                                     \
} while (0)

// --- int8 GEMM: 256x256, BK=128, 8 waves, 32x32x32 MFMA, frag-pipelined ---
__global__ __launch_bounds__(512, 2) void gemm_i8_kernel(const int8_t* __restrict__ A,
                                                         const int8_t* __restrict__ W,
                                                         const int* __restrict__ rowsum,
                                                         float* __restrict__ out) {
    extern __shared__ int8_t lds[];   // 2 * 64 KB

    // XCD-aware swizzle: 512 wgs, 8 XCDs, 64 contiguous tiles per XCD
    int bid = blockIdx.x;
    int wg = (bid & 7) * 64 + (bid >> 3);
    int tm = wg >> 3;
    int tn = wg & 7;
    int browG = tm * BM;
    int bcolG = tn * BN;

    int tid  = threadIdx.x;
    int lane = tid & 63;
    int wv   = tid >> 6;
    int wr = wv >> 2, wc = wv & 3;    // 2x4 waves, wave tile 128x64
    int l31 = lane & 31;
    int hi  = lane >> 5;              // 0..1

    // staging (as r5/r7, verified): thread covers rows (tid>>3)+s*64, chunk
    // col tid&7; LDS chunk (r,c) holds global chunk (r, c ^ ((r>>1)&7)).
    int csw = (tid & 7) ^ ((tid >> 4) & 7);
    const int8_t* gA = A + (size_t)(browG + (tid >> 3)) * IN_DIM + csw * 16;
    const int8_t* gB = W + (size_t)(bcolG + (tid >> 3)) * IN_DIM + csw * 16;
    const int t16 = tid * 16;

    // ds_read: A row = wr*128 + m*32 + l31; B row(outcol) = wc*64 + n*32 + l31;
    // k-chunk kc = ks*2 + hi, swizzled kc ^ ((row>>1)&7) == kc ^ ((l31>>1)&7).
    const int xsw = (l31 >> 1) & 7;
    const int k0 = (((0 + hi) ^ xsw) << 4);
    const int k1 = (((2 + hi) ^ xsw) << 4);
    const int k2 = (((4 + hi) ^ xsw) << 4);
    const int k3 = (((6 + hi) ^ xsw) << 4);
    const int arowO = (wr * 128 + l31) * BK;   // + m*4096
    const int browO = (wc * 64 + l31) * BK;    // + n*4096

    i32x16 acc[4][2];
#pragma unroll
    for (int m = 0; m < 4; ++m)
#pragma unroll
        for (int n = 0; n < 2; ++n)
            acc[m][n] = (i32x16){0, 0, 0, 0, 0, 0, 0, 0, 0, 0, 0, 0, 0, 0, 0, 0};
    i32x4 aX[4], aY[4], bX[2], bY[2];

    // ---- prologue: stage tile 0 into buf0 ----
    async16(gA, lds + t16);
    async16(gA + 131072, lds + 8192 + t16);
    async16(gA + 262144, lds + 16384 + t16);
    async16(gA + 393216, lds + 24576 + t16);
    async16(gB, lds + ATILE + t16);
    async16(gB + 131072, lds + ATILE + 8192 + t16);
    async16(gB + 262144, lds + ATILE + 16384 + t16);
    async16(gB + 393216, lds + ATILE + 24576 + t16);

    // ---- main loop: tiles 0..14 stage 1..15; tile 15 no staging ----
#pragma unroll 1
    for (int i = 0; i < 7; ++i) {
        DO_TILE(0, 2 * i + 1, 1);
        DO_TILE(1, 2 * i + 2, 1);
    }
    DO_TILE(0, 15, 1);
    DO_TILE(1, 0, 0);

    // ---- epilogue: zero-point, scale, photodetect square, ReLUN(6) ----
    // C/D 32x32 map: col = lane&31, row = (reg&3) + 8*(reg>>2) + 4*(lane>>5)
    const float scale = (float)(2.0 / 32385.0);
#pragma unroll
    for (int n = 0; n < 2; ++n) {
        int col = bcolG + wc * 64 + n * 32 + l31;
        int rs128 = rowsum[col] << 7;
#pragma unroll
        for (int m = 0; m < 4; ++m) {
            int rb = browG + wr * 128 + m * 32 + hi * 4;
#pragma unroll
            for (int r = 0; r < 16; ++r) {
                int row = rb + (r & 3) + 8 * (r >> 2);
                float f = (float)(acc[m][n][r] + rs128) * scale;
                f = f * f;
                f = fminf(f, 6.0f);
                out[(size_t)row * OUT_DIM + col] = f;
            }
        }
    }
}

extern "C" void kernel_launch(void* const* d_in, const int* in_sizes, int n_in,
                              void* d_out, int out_size, void* d_ws, size_t ws_size,
                              hipStream_t stream) {
    const float* x  = (const float*)d_in[0];   // [16384, 2048] f32
    const float* wt = (const float*)d_in[1];   // [256, 256, 8, 8] f32
    float* out = (float*)d_out;                // [16384, 2048] f32

    char* ws = (char*)d_ws;
    int8_t* xq = (int8_t*)ws;                                   // 32 MB
    int8_t* wq = (int8_t*)(ws + (size_t)B_DIM * IN_DIM);        // 4 MB
    int*    rowsum = (int*)(ws + (size_t)B_DIM * IN_DIM
                               + (size_t)OUT_DIM * IN_DIM);     // 8 KB

    hipMemsetAsync(rowsum, 0, OUT_DIM * sizeof(int), stream);
    quant_x_kernel<<<(B_DIM * IN_DIM / 16) / 256, 256, 0, stream>>>(x, xq);
    quant_w_kernel<<<256, 256, 0, stream>>>(wt, wq, rowsum);
    gemm_i8_kernel<<<(B_DIM / BM) * (OUT_DIM / BN), 512, 2 * BUFB, stream>>>(xq, wq, rowsum, out);
}